// Round 10
// baseline (127.632 us; speedup 1.0000x reference)
//
#include <hip/hip_runtime.h>
#include <stdint.h>

#define MIN_NORM 1e-15f
#define MARGIN 9.0f
#define DIM 64
#define B_ROWS 1024
#define NC 1024
#define N_ENT 200000
#define CONV_BLOCKS ((N_ENT + 63) / 64)   // 3125
#define HEAD_BLOCKS (B_ROWS / 4)          // 256

typedef float v2f __attribute__((ext_vector_type(2)));

__device__ inline float wave_reduce_sum(float v) {
    #pragma unroll
    for (int off = 32; off > 0; off >>= 1) v += __shfl_xor(v, off, 64);
    return v;
}

// e2m1 decode (ALU fallback): values {0,.5,1,1.5,2,3,4,6} x sign
__device__ inline float dec_e2m1(uint32_t nib) {
    uint32_t em = nib & 7u;
    float v = em < 2u ? (em ? 0.5f : 0.0f)
            : em < 4u ? (em == 2u ? 1.0f : 1.5f)
            : em < 6u ? (em == 4u ? 2.0f : 3.0f)
                      : (em == 6u ? 4.0f : 6.0f);
    return (nib & 8u) ? -v : v;
}

// ---------------- head pipeline body: one wave per output row ----------------
__device__ inline void head_body(
    int row,
    const int* __restrict__ u_idx, const int* __restrict__ r_idx,
    const float* __restrict__ emb, const float* __restrict__ rel_diag,
    const float* __restrict__ rb1, const float* __restrict__ rb2,
    const float* __restrict__ bias_head, const float* __restrict__ sigma,
    float* __restrict__ head_out, float* __restrict__ scal_out)
{
    const int lane = threadIdx.x & 63;
    const int u = u_idx[row];
    const int r = r_idx[row];

    float x = emb[(long)u * DIM + lane];
    {
        float n2 = wave_reduce_sum(x * x);
        float un = fmaxf(sqrtf(n2), MIN_NORM);
        x = tanhf(un) / un * x;
    }
    float y = rb1[(long)r * DIM + lane];
    {
        float n2 = wave_reduce_sum(y * y);
        float un = fmaxf(sqrtf(n2), MIN_NORM);
        y = tanhf(un) / un * y;
    }
    {
        float x2 = wave_reduce_sum(x * x);
        float y2 = wave_reduce_sum(y * y);
        float xy = wave_reduce_sum(x * y);
        float den = 1.0f + 2.0f * xy + x2 * y2;
        x = ((1.0f + 2.0f * xy + y2) * x + (1.0f - x2) * y) / fmaxf(den, MIN_NORM);
    }
    {
        float g  = rel_diag[(long)r * DIM + lane];
        float go = __shfl_xor(g, 1, 64);
        float xo = __shfl_xor(x, 1, 64);
        float gn = fmaxf(sqrtf(g * g + go * go), MIN_NORM);
        x = ((lane & 1) ? (g * xo + go * x) : (g * x - go * xo)) / gn;
    }
    float z = rb2[(long)r * DIM + lane];
    {
        float n2 = wave_reduce_sum(z * z);
        float un = fmaxf(sqrtf(n2), MIN_NORM);
        z = tanhf(un) / un * z;
    }
    {
        float x2 = wave_reduce_sum(x * x);
        float y2 = wave_reduce_sum(z * z);
        float xy = wave_reduce_sum(x * z);
        float den = 1.0f + 2.0f * xy + x2 * y2;
        x = ((1.0f + 2.0f * xy + y2) * x + (1.0f - x2) * z) / fmaxf(den, MIN_NORM);
    }
    float h2 = wave_reduce_sum(x * x);
    head_out[(long)row * DIM + lane] = x;
    if (lane == 0) {
        scal_out[row * 4 + 0] = h2;
        scal_out[row * 4 + 1] = logf(fmaxf(1.0f - h2, MIN_NORM));
        scal_out[row * 4 + 2] = 1.0f / (1.0f + expf(-sigma[r]));
        scal_out[row * 4 + 3] = bias_head[u];
    }
}

// ------- fused: [0, CONV_BLOCKS): emb -> packed 64 B rows
//                [CONV_BLOCKS, +HEAD_BLOCKS): head pipeline -------
// Row layout (64 B stride): bytes [0,32) = 64 fp4 codes in element order
// (dword d holds elems [8d,8d+8)); bytes [32,48) = float4 {inv_scale,
// bias_tail, sum(code^2), 0}; bytes [48,64) pad.
__global__ __launch_bounds__(256) void prep_kernel(
    const int* __restrict__ u_idx, const int* __restrict__ r_idx,
    const float* __restrict__ emb, const float* __restrict__ rel_diag,
    const float* __restrict__ rb1, const float* __restrict__ rb2,
    const float* __restrict__ bias_head, const float* __restrict__ sigma,
    const float* __restrict__ bias_tail,
    uint32_t* __restrict__ tau,
    float* __restrict__ head_out, float* __restrict__ scal_out)
{
    const int t = threadIdx.x;
    if (blockIdx.x >= CONV_BLOCKS) {
        int row = (blockIdx.x - CONV_BLOCKS) * 4 + (t >> 6);
        head_body(row, u_idx, r_idx, emb, rel_diag, rb1, rb2,
                  bias_head, sigma, head_out, scal_out);
        return;
    }
    const int g = t >> 2, sub = t & 3;
    const long row = (long)blockIdx.x * 64 + g;
    if (row >= N_ENT) return;

    const float4* p = (const float4*)(emb + row * DIM);
    float4 c[4];
    #pragma unroll
    for (int k = 0; k < 4; ++k) c[k] = p[4 * sub + k];   // contiguous 16 elems

    float n2 = 0.0f, m = 0.0f;
    #pragma unroll
    for (int k = 0; k < 4; ++k) {
        n2 = fmaf(c[k].x, c[k].x, n2); n2 = fmaf(c[k].y, c[k].y, n2);
        n2 = fmaf(c[k].z, c[k].z, n2); n2 = fmaf(c[k].w, c[k].w, n2);
        m = fmaxf(m, fmaxf(fmaxf(fabsf(c[k].x), fabsf(c[k].y)),
                           fmaxf(fabsf(c[k].z), fabsf(c[k].w))));
    }
    n2 += __shfl_xor(n2, 1, 64); n2 += __shfl_xor(n2, 2, 64);
    m = fmaxf(m, __shfl_xor(m, 1, 64));
    m = fmaxf(m, __shfl_xor(m, 2, 64));

    const float un = fmaxf(sqrtf(n2), MIN_NORM);
    const float s_tanh = tanhf(un) / un;
    const float maxtau = fmaxf(m * s_tanh, 1e-30f);
    const float enc = s_tanh * (6.0f / maxtau);   // e -> code units

    uint32_t w0 = 0, w1 = 0;
    #pragma unroll
    for (int k = 0; k < 4; ++k) {
        const float xs[4] = {c[k].x, c[k].y, c[k].z, c[k].w};
        #pragma unroll
        for (int mcomp = 0; mcomp < 4; ++mcomp) {
            const int j = 4 * k + mcomp;
            const float x = xs[mcomp];
            const float tv = fabsf(x) * enc;
            uint32_t code = (uint32_t)(tv > 0.25f) + (uint32_t)(tv > 0.75f)
                          + (uint32_t)(tv > 1.25f) + (uint32_t)(tv > 1.75f)
                          + (uint32_t)(tv > 2.5f)  + (uint32_t)(tv > 3.5f)
                          + (uint32_t)(tv > 5.0f);
            uint32_t nib = code | ((__float_as_uint(x) >> 31) << 3);
            if (j < 8) w0 |= nib << (4 * j);
            else       w1 |= nib << (4 * (j - 8));
        }
    }
    // sum of squared DECODED code values for this lane's 16 elems
    float qs = 0.0f;
    {
        const uint32_t w[2] = {w0, w1};
        #pragma unroll
        for (int dw = 0; dw < 2; ++dw) {
#if __has_builtin(__builtin_amdgcn_cvt_scalef32_pk_f32_fp4)
            v2f p0 = __builtin_amdgcn_cvt_scalef32_pk_f32_fp4(w[dw], 1.0f, 0);
            v2f p1 = __builtin_amdgcn_cvt_scalef32_pk_f32_fp4(w[dw], 1.0f, 1);
            v2f p2 = __builtin_amdgcn_cvt_scalef32_pk_f32_fp4(w[dw], 1.0f, 2);
            v2f p3 = __builtin_amdgcn_cvt_scalef32_pk_f32_fp4(w[dw], 1.0f, 3);
            qs = fmaf(p0.x, p0.x, qs); qs = fmaf(p0.y, p0.y, qs);
            qs = fmaf(p1.x, p1.x, qs); qs = fmaf(p1.y, p1.y, qs);
            qs = fmaf(p2.x, p2.x, qs); qs = fmaf(p2.y, p2.y, qs);
            qs = fmaf(p3.x, p3.x, qs); qs = fmaf(p3.y, p3.y, qs);
#else
            #pragma unroll
            for (int n = 0; n < 8; ++n) {
                float val = dec_e2m1((w[dw] >> (4 * n)) & 15u);
                qs = fmaf(val, val, qs);
            }
#endif
        }
    }
    qs += __shfl_xor(qs, 1, 64); qs += __shfl_xor(qs, 2, 64);

    ((uint2*)tau)[row * 8 + sub] = make_uint2(w0, w1);   // bytes [8sub, 8sub+8)
    if (sub == 0)
        ((float4*)tau)[row * 4 + 2] =                    // bytes [32,48)
            make_float4(maxtau * (1.0f / 6.0f), bias_tail[row], qs, 0.0f);
}

// ---------------- hot gather: ONE vmem instruction per candidate ----------------
// 4-lane group loads the full 64 B row as one coalesced uint4/lane transaction:
// lane0 = elems[0,32), lane1 = elems[32,64), lane2 = scalar float4, lane3 = pad.
// Lanes 2-3 are h=0 gated out of the dot; scalars pulled from lane2 via shfl.
__global__ __launch_bounds__(256) void score_fp4_kernel(
    const int* __restrict__ v_idx, const uint32_t* __restrict__ tau,
    const float* __restrict__ head, const float* __restrict__ scal,
    float* __restrict__ out)
{
    const int b = blockIdx.y;
    const int base = blockIdx.x * 512;          // 512 candidates per block
    const int t = threadIdx.x;
    const int g = t >> 2, sub = t & 3;
    const int srcl = ((t & 63) & ~3) | 2;       // lane2 of my group (wave-local)

    __shared__ float4 sh[DIM / 4];
    __shared__ float ss[4];
    if (t < DIM / 4) sh[t] = ((const float4*)(head + (long)b * DIM))[t];
    if (t < 4) ss[t] = scal[b * 4 + t];

    const int4 va = ((const int4*)(v_idx + (long)b * NC + base))[2 * g];
    const int4 vb = ((const int4*)(v_idx + (long)b * NC + base))[2 * g + 1];
    const int vv[8] = {va.x, va.y, va.z, va.w, vb.x, vb.y, vb.z, vb.w};

    // 8 scattered uint4 loads: candidate j's full 64 B line in one transaction
    uint4 q[8];
    #pragma unroll
    for (int j = 0; j < 8; ++j)
        q[j] = ((const uint4*)tau)[(long)vv[j] * 4 + sub];

    __syncthreads();

    // head fragment: lane0 -> elems [0,32), lane1 -> [32,64); lanes 2,3 -> 0
    const float gate = (sub < 2) ? 1.0f : 0.0f;
    float4 h[8];
    #pragma unroll
    for (int k = 0; k < 8; ++k) {
        float4 v = sh[(sub & 1) * 8 + k];
        h[k] = make_float4(v.x * gate, v.y * gate, v.z * gate, v.w * gate);
    }

    float dot[8], fi[8], fb[8], fs[8];
    #pragma unroll
    for (int j = 0; j < 8; ++j) {
        float d = 0.0f;
        const uint32_t w[4] = {q[j].x, q[j].y, q[j].z, q[j].w};
        #pragma unroll
        for (int dw = 0; dw < 4; ++dw) {
#if __has_builtin(__builtin_amdgcn_cvt_scalef32_pk_f32_fp4)
            v2f p0 = __builtin_amdgcn_cvt_scalef32_pk_f32_fp4(w[dw], 1.0f, 0);
            v2f p1 = __builtin_amdgcn_cvt_scalef32_pk_f32_fp4(w[dw], 1.0f, 1);
            v2f p2 = __builtin_amdgcn_cvt_scalef32_pk_f32_fp4(w[dw], 1.0f, 2);
            v2f p3 = __builtin_amdgcn_cvt_scalef32_pk_f32_fp4(w[dw], 1.0f, 3);
            const float4 hA = h[2 * dw], hB = h[2 * dw + 1];
            d = fmaf(hA.x, p0.x, d); d = fmaf(hA.y, p0.y, d);
            d = fmaf(hA.z, p1.x, d); d = fmaf(hA.w, p1.y, d);
            d = fmaf(hB.x, p2.x, d); d = fmaf(hB.y, p2.y, d);
            d = fmaf(hB.z, p3.x, d); d = fmaf(hB.w, p3.y, d);
#else
            const float* hp = (const float*)&h[2 * dw];
            #pragma unroll
            for (int n = 0; n < 8; ++n) {
                float val = dec_e2m1((w[dw] >> (4 * n)) & 15u);
                d = fmaf(hp[n], val, d);
            }
#endif
        }
        // butterfly: (0+1) then (+2,+3 zeros) -> all 4 lanes hold full dot
        d += __shfl_xor(d, 1, 64);
        d += __shfl_xor(d, 2, 64);
        dot[j] = d;
        // scalars ride lane2's registers of the SAME line (no extra touch)
        fi[j] = __shfl(__uint_as_float(q[j].x), srcl, 64);   // inv_scale
        fb[j] = __shfl(__uint_as_float(q[j].y), srcl, 64);   // bias_tail
        fs[j] = __shfl(__uint_as_float(q[j].z), srcl, 64);   // sum(code^2)
    }

    const float h2 = ss[0], ldh = ss[1], sig = ss[2], bh = ss[3];

    // candidate A: j == sub
    {
        const float Dc = (sub == 0) ? dot[0] : (sub == 1) ? dot[1] : (sub == 2) ? dot[2] : dot[3];
        const float iv = (sub == 0) ? fi[0] : (sub == 1) ? fi[1] : (sub == 2) ? fi[2] : fi[3];
        const float bt = (sub == 0) ? fb[0] : (sub == 1) ? fb[1] : (sub == 2) ? fb[2] : fb[3];
        const float sq = (sub == 0) ? fs[0] : (sub == 1) ? fs[1] : (sub == 2) ? fs[2] : fs[3];
        const float D  = Dc * iv;
        const float t2 = sq * iv * iv;
        const float lt = logf(fmaxf(1.0f - t2, MIN_NORM));
        const float num = h2 + t2 - 2.0f * D;
        const float dist = logf(fmaxf(num, MIN_NORM)) - sig * lt - (1.0f - sig) * ldh;
        out[(long)b * NC + base + 8 * g + sub] = MARGIN - dist + bh + bt;
    }
    // candidate B: j == sub + 4
    {
        const float Dc = (sub == 0) ? dot[4] : (sub == 1) ? dot[5] : (sub == 2) ? dot[6] : dot[7];
        const float iv = (sub == 0) ? fi[4] : (sub == 1) ? fi[5] : (sub == 2) ? fi[6] : fi[7];
        const float bt = (sub == 0) ? fb[4] : (sub == 1) ? fb[5] : (sub == 2) ? fb[6] : fb[7];
        const float sq = (sub == 0) ? fs[4] : (sub == 1) ? fs[5] : (sub == 2) ? fs[6] : fs[7];
        const float D  = Dc * iv;
        const float t2 = sq * iv * iv;
        const float lt = logf(fmaxf(1.0f - t2, MIN_NORM));
        const float num = h2 + t2 - 2.0f * D;
        const float dist = logf(fmaxf(num, MIN_NORM)) - sig * lt - (1.0f - sig) * ldh;
        out[(long)b * NC + base + 8 * g + 4 + sub] = MARGIN - dist + bh + bt;
    }
}

// ---------------- fallback fp32 path, used only if ws too small ----------------
__global__ __launch_bounds__(256) void head_kernel(
    const int* __restrict__ u_idx, const int* __restrict__ r_idx,
    const float* __restrict__ emb, const float* __restrict__ rel_diag,
    const float* __restrict__ rb1, const float* __restrict__ rb2,
    const float* __restrict__ bias_head, const float* __restrict__ sigma,
    float* __restrict__ head_out, float* __restrict__ scal_out)
{
    const int row = blockIdx.x * 4 + (threadIdx.x >> 6);
    if (row >= B_ROWS) return;
    head_body(row, u_idx, r_idx, emb, rel_diag, rb1, rb2,
              bias_head, sigma, head_out, scal_out);
}

__global__ __launch_bounds__(256) void score_fp32_kernel(
    const int* __restrict__ v_idx, const float* __restrict__ emb,
    const float* __restrict__ bias_tail,
    const float* __restrict__ head, const float* __restrict__ scal,
    float* __restrict__ out)
{
    const int b = blockIdx.y;
    const int base = blockIdx.x * 256;
    const int t = threadIdx.x;
    const int g = t >> 2, sub = t & 3;

    __shared__ float4 sh[DIM / 4];
    __shared__ float ss[4];
    if (t < DIM / 4) sh[t] = ((const float4*)(head + (long)b * DIM))[t];
    if (t < 4) ss[t] = scal[b * 4 + t];

    const int4 v4 = ((const int4*)(v_idx + (long)b * NC + base))[g];
    const int v0 = v4.x, v1 = v4.y, v2 = v4.z, v3 = v4.w;
    __syncthreads();

    float4 h[4];
    #pragma unroll
    for (int k = 0; k < 4; ++k) h[k] = sh[4 * k + sub];

    float4 e[4][4];
    {
        const float4* p0 = (const float4*)(emb + (long)v0 * DIM);
        const float4* p1 = (const float4*)(emb + (long)v1 * DIM);
        const float4* p2 = (const float4*)(emb + (long)v2 * DIM);
        const float4* p3 = (const float4*)(emb + (long)v3 * DIM);
        #pragma unroll
        for (int k = 0; k < 4; ++k) {
            e[0][k] = p0[4 * k + sub];
            e[1][k] = p1[4 * k + sub];
            e[2][k] = p2[4 * k + sub];
            e[3][k] = p3[4 * k + sub];
        }
    }

    float dot[4], e2[4];
    #pragma unroll
    for (int j = 0; j < 4; ++j) {
        float d = 0.0f, qq = 0.0f;
        #pragma unroll
        for (int k = 0; k < 4; ++k) {
            float4 ee = e[j][k]; float4 hh = h[k];
            d = fmaf(hh.x, ee.x, d); d = fmaf(hh.y, ee.y, d);
            d = fmaf(hh.z, ee.z, d); d = fmaf(hh.w, ee.w, d);
            qq = fmaf(ee.x, ee.x, qq); qq = fmaf(ee.y, ee.y, qq);
            qq = fmaf(ee.z, ee.z, qq); qq = fmaf(ee.w, ee.w, qq);
        }
        d += __shfl_xor(d, 1, 64); d += __shfl_xor(d, 2, 64);
        qq += __shfl_xor(qq, 1, 64); qq += __shfl_xor(qq, 2, 64);
        dot[j] = d; e2[j] = qq;
    }

    const float D  = (sub == 0) ? dot[0] : (sub == 1) ? dot[1] : (sub == 2) ? dot[2] : dot[3];
    const float E  = (sub == 0) ? e2[0]  : (sub == 1) ? e2[1]  : (sub == 2) ? e2[2]  : e2[3];
    const int myv  = (sub == 0) ? v0     : (sub == 1) ? v1     : (sub == 2) ? v2     : v3;

    const float h2 = ss[0], ldh = ss[1], sig = ss[2], bh = ss[3];
    const float un = fmaxf(sqrtf(E), MIN_NORM);
    const float tn = tanhf(un);
    const float s = tn / un;
    const float t2 = tn * tn;
    const float num = h2 + t2 - 2.0f * s * D;
    const float dist = logf(fmaxf(num, MIN_NORM))
                     - sig * logf(fmaxf(1.0f - t2, MIN_NORM))
                     - (1.0f - sig) * ldh;
    out[(long)b * NC + base + t] = MARGIN - dist + bh + bias_tail[myv];
}

extern "C" void kernel_launch(void* const* d_in, const int* in_sizes, int n_in,
                              void* d_out, int out_size, void* d_ws, size_t ws_size,
                              hipStream_t stream) {
    const int*   u_idx     = (const int*)d_in[0];
    const int*   r_idx     = (const int*)d_in[1];
    const int*   v_idx     = (const int*)d_in[2];
    const float* emb       = (const float*)d_in[3];
    const float* rel_diag  = (const float*)d_in[4];
    const float* rb1       = (const float*)d_in[5];
    const float* rb2       = (const float*)d_in[6];
    const float* bias_head = (const float*)d_in[7];
    const float* bias_tail = (const float*)d_in[8];
    const float* sigma     = (const float*)d_in[9];

    char* ws = (char*)d_ws;
    float*    head = (float*)ws;                 // 256 KB
    float*    scal = (float*)(ws + 262144);      // 16 KB
    uint32_t* tau  = (uint32_t*)(ws + 278528);   // 12.8 MB packed 64 B rows
    const size_t need = 278528 + (size_t)N_ENT * 64;

    if (ws_size >= need) {
        prep_kernel<<<CONV_BLOCKS + HEAD_BLOCKS, 256, 0, stream>>>(
            u_idx, r_idx, emb, rel_diag, rb1, rb2, bias_head, sigma,
            bias_tail, tau, head, scal);
        score_fp4_kernel<<<dim3(NC / 512, B_ROWS), 256, 0, stream>>>(
            v_idx, tau, head, scal, (float*)d_out);
    } else {
        head_kernel<<<HEAD_BLOCKS, 256, 0, stream>>>(
            u_idx, r_idx, emb, rel_diag, rb1, rb2, bias_head, sigma, head, scal);
        score_fp32_kernel<<<dim3(NC / 256, B_ROWS), 256, 0, stream>>>(
            v_idx, emb, bias_tail, head, scal, (float*)d_out);
    }
}

// Round 11
// 124.889 us; speedup vs baseline: 1.0220x; 1.0220x over previous
//
#include <hip/hip_runtime.h>
#include <stdint.h>

#define MIN_NORM 1e-15f
#define MARGIN 9.0f
#define DIM 64
#define B_ROWS 1024
#define NC 1024
#define N_ENT 200000
#define CONV_BLOCKS ((N_ENT + 63) / 64)   // 3125
#define HEAD_BLOCKS (B_ROWS / 4)          // 256

typedef float v2f __attribute__((ext_vector_type(2)));

__device__ inline float wave_reduce_sum(float v) {
    #pragma unroll
    for (int off = 32; off > 0; off >>= 1) v += __shfl_xor(v, off, 64);
    return v;
}

// e2m1 decode (ALU fallback): values {0,.5,1,1.5,2,3,4,6} x sign
__device__ inline float dec_e2m1(uint32_t nib) {
    uint32_t em = nib & 7u;
    float v = em < 2u ? (em ? 0.5f : 0.0f)
            : em < 4u ? (em == 2u ? 1.0f : 1.5f)
            : em < 6u ? (em == 4u ? 2.0f : 3.0f)
                      : (em == 6u ? 4.0f : 6.0f);
    return (nib & 8u) ? -v : v;
}

// ---------------- head pipeline body: one wave per output row ----------------
__device__ inline void head_body(
    int row,
    const int* __restrict__ u_idx, const int* __restrict__ r_idx,
    const float* __restrict__ emb, const float* __restrict__ rel_diag,
    const float* __restrict__ rb1, const float* __restrict__ rb2,
    const float* __restrict__ bias_head, const float* __restrict__ sigma,
    float* __restrict__ head_out, float* __restrict__ scal_out)
{
    const int lane = threadIdx.x & 63;
    const int u = u_idx[row];
    const int r = r_idx[row];

    float x = emb[(long)u * DIM + lane];
    {
        float n2 = wave_reduce_sum(x * x);
        float un = fmaxf(sqrtf(n2), MIN_NORM);
        x = tanhf(un) / un * x;
    }
    float y = rb1[(long)r * DIM + lane];
    {
        float n2 = wave_reduce_sum(y * y);
        float un = fmaxf(sqrtf(n2), MIN_NORM);
        y = tanhf(un) / un * y;
    }
    {
        float x2 = wave_reduce_sum(x * x);
        float y2 = wave_reduce_sum(y * y);
        float xy = wave_reduce_sum(x * y);
        float den = 1.0f + 2.0f * xy + x2 * y2;
        x = ((1.0f + 2.0f * xy + y2) * x + (1.0f - x2) * y) / fmaxf(den, MIN_NORM);
    }
    {
        float g  = rel_diag[(long)r * DIM + lane];
        float go = __shfl_xor(g, 1, 64);
        float xo = __shfl_xor(x, 1, 64);
        float gn = fmaxf(sqrtf(g * g + go * go), MIN_NORM);
        x = ((lane & 1) ? (g * xo + go * x) : (g * x - go * xo)) / gn;
    }
    float z = rb2[(long)r * DIM + lane];
    {
        float n2 = wave_reduce_sum(z * z);
        float un = fmaxf(sqrtf(n2), MIN_NORM);
        z = tanhf(un) / un * z;
    }
    {
        float x2 = wave_reduce_sum(x * x);
        float y2 = wave_reduce_sum(z * z);
        float xy = wave_reduce_sum(x * z);
        float den = 1.0f + 2.0f * xy + x2 * y2;
        x = ((1.0f + 2.0f * xy + y2) * x + (1.0f - x2) * z) / fmaxf(den, MIN_NORM);
    }
    float h2 = wave_reduce_sum(x * x);
    head_out[(long)row * DIM + lane] = x;
    if (lane == 0) {
        scal_out[row * 4 + 0] = h2;
        scal_out[row * 4 + 1] = logf(fmaxf(1.0f - h2, MIN_NORM));
        scal_out[row * 4 + 2] = 1.0f / (1.0f + expf(-sigma[r]));
        scal_out[row * 4 + 3] = bias_head[u];
    }
}

// ------- fused: [0, CONV_BLOCKS): emb -> fp4(e2m1) tails (32 B/row) + sb table
//                [CONV_BLOCKS, +HEAD_BLOCKS): head pipeline -------
// Layout: lane sub owns CONTIGUOUS elements [16*sub, 16*sub+16); packs them as
// 2 dwords (element j -> dword j/8, nibble j%8, low nibble first).
// sb[v] = {inv_scale = maxtau/6, bias_tail[v]}.
__global__ __launch_bounds__(256) void prep_kernel(
    const int* __restrict__ u_idx, const int* __restrict__ r_idx,
    const float* __restrict__ emb, const float* __restrict__ rel_diag,
    const float* __restrict__ rb1, const float* __restrict__ rb2,
    const float* __restrict__ bias_head, const float* __restrict__ sigma,
    const float* __restrict__ bias_tail,
    uint32_t* __restrict__ tau, float2* __restrict__ sb,
    float* __restrict__ head_out, float* __restrict__ scal_out)
{
    const int t = threadIdx.x;
    if (blockIdx.x >= CONV_BLOCKS) {
        int row = (blockIdx.x - CONV_BLOCKS) * 4 + (t >> 6);
        head_body(row, u_idx, r_idx, emb, rel_diag, rb1, rb2,
                  bias_head, sigma, head_out, scal_out);
        return;
    }
    const int g = t >> 2, sub = t & 3;
    const long row = (long)blockIdx.x * 64 + g;
    if (row >= N_ENT) return;

    const float4* p = (const float4*)(emb + row * DIM);
    float4 c[4];
    #pragma unroll
    for (int k = 0; k < 4; ++k) c[k] = p[4 * sub + k];   // contiguous 16 elems

    float n2 = 0.0f, m = 0.0f;
    #pragma unroll
    for (int k = 0; k < 4; ++k) {
        n2 = fmaf(c[k].x, c[k].x, n2); n2 = fmaf(c[k].y, c[k].y, n2);
        n2 = fmaf(c[k].z, c[k].z, n2); n2 = fmaf(c[k].w, c[k].w, n2);
        m = fmaxf(m, fmaxf(fmaxf(fabsf(c[k].x), fabsf(c[k].y)),
                           fmaxf(fabsf(c[k].z), fabsf(c[k].w))));
    }
    n2 += __shfl_xor(n2, 1, 64); n2 += __shfl_xor(n2, 2, 64);
    m = fmaxf(m, __shfl_xor(m, 1, 64));
    m = fmaxf(m, __shfl_xor(m, 2, 64));

    const float un = fmaxf(sqrtf(n2), MIN_NORM);
    const float s_tanh = tanhf(un) / un;
    const float maxtau = fmaxf(m * s_tanh, 1e-30f);
    const float enc = s_tanh * (6.0f / maxtau);   // e -> code units

    uint32_t w0 = 0, w1 = 0;
    #pragma unroll
    for (int k = 0; k < 4; ++k) {
        const float xs[4] = {c[k].x, c[k].y, c[k].z, c[k].w};
        #pragma unroll
        for (int mcomp = 0; mcomp < 4; ++mcomp) {
            const int j = 4 * k + mcomp;
            const float x = xs[mcomp];
            const float tv = fabsf(x) * enc;
            uint32_t code = (uint32_t)(tv > 0.25f) + (uint32_t)(tv > 0.75f)
                          + (uint32_t)(tv > 1.25f) + (uint32_t)(tv > 1.75f)
                          + (uint32_t)(tv > 2.5f)  + (uint32_t)(tv > 3.5f)
                          + (uint32_t)(tv > 5.0f);
            uint32_t nib = code | ((__float_as_uint(x) >> 31) << 3);
            if (j < 8) w0 |= nib << (4 * j);
            else       w1 |= nib << (4 * (j - 8));
        }
    }
    ((uint2*)tau)[row * 4 + sub] = make_uint2(w0, w1);
    if (sub == 0)
        sb[row] = make_float2(maxtau * (1.0f / 6.0f), bias_tail[row]);
}

// ---------------- hot gather: fp4 tails, 8 candidates per 4-lane group ----------------
// ~11 scattered loads in flight per thread; dot & |q|^2 in code units, scale
// applied once in the epilogue by the owning lane (2 cands/lane).
__global__ __launch_bounds__(256) void score_fp4_kernel(
    const int* __restrict__ v_idx, const uint32_t* __restrict__ tau,
    const float2* __restrict__ sb,
    const float* __restrict__ head, const float* __restrict__ scal,
    float* __restrict__ out)
{
    const int b = blockIdx.y;
    const int base = blockIdx.x * 512;          // 512 candidates per block
    const int t = threadIdx.x;
    const int g = t >> 2, sub = t & 3;

    __shared__ float4 sh[DIM / 4];
    __shared__ float ss[4];
    if (t < DIM / 4) sh[t] = ((const float4*)(head + (long)b * DIM))[t];
    if (t < 4) ss[t] = scal[b * 4 + t];

    const int4 va = ((const int4*)(v_idx + (long)b * NC + base))[2 * g];
    const int4 vb = ((const int4*)(v_idx + (long)b * NC + base))[2 * g + 1];
    const int vv[8] = {va.x, va.y, va.z, va.w, vb.x, vb.y, vb.z, vb.w};

    // 8 scattered 8 B gathers, issued back-to-back
    uint2 q[8];
    #pragma unroll
    for (int j = 0; j < 8; ++j)
        q[j] = ((const uint2*)tau)[(long)vv[j] * 4 + sub];

    // lane sub owns candidates sub and sub+4
    const float2 sb0 = sb[vv[sub]];
    const float2 sb1 = sb[vv[sub + 4]];

    __syncthreads();

    // head fragment: contiguous elements [16*sub, 16*sub+16)
    float4 h[4];
    #pragma unroll
    for (int k = 0; k < 4; ++k) h[k] = sh[4 * sub + k];

    float dot[8], qq2[8];
    #pragma unroll
    for (int j = 0; j < 8; ++j) {
        float d = 0.0f, qq = 0.0f;
#if __has_builtin(__builtin_amdgcn_cvt_scalef32_pk_f32_fp4)
        const uint32_t w[2] = {q[j].x, q[j].y};
        #pragma unroll
        for (int dw = 0; dw < 2; ++dw) {
            v2f p0 = __builtin_amdgcn_cvt_scalef32_pk_f32_fp4(w[dw], 1.0f, 0);
            v2f p1 = __builtin_amdgcn_cvt_scalef32_pk_f32_fp4(w[dw], 1.0f, 1);
            v2f p2 = __builtin_amdgcn_cvt_scalef32_pk_f32_fp4(w[dw], 1.0f, 2);
            v2f p3 = __builtin_amdgcn_cvt_scalef32_pk_f32_fp4(w[dw], 1.0f, 3);
            const float4 hA = h[2 * dw], hB = h[2 * dw + 1];
            d = fmaf(hA.x, p0.x, d); d = fmaf(hA.y, p0.y, d);
            d = fmaf(hA.z, p1.x, d); d = fmaf(hA.w, p1.y, d);
            d = fmaf(hB.x, p2.x, d); d = fmaf(hB.y, p2.y, d);
            d = fmaf(hB.z, p3.x, d); d = fmaf(hB.w, p3.y, d);
            qq = fmaf(p0.x, p0.x, qq); qq = fmaf(p0.y, p0.y, qq);
            qq = fmaf(p1.x, p1.x, qq); qq = fmaf(p1.y, p1.y, qq);
            qq = fmaf(p2.x, p2.x, qq); qq = fmaf(p2.y, p2.y, qq);
            qq = fmaf(p3.x, p3.x, qq); qq = fmaf(p3.y, p3.y, qq);
        }
#else
        const uint32_t w[2] = {q[j].x, q[j].y};
        #pragma unroll
        for (int dw = 0; dw < 2; ++dw) {
            const float* hp = (const float*)&h[2 * dw];
            #pragma unroll
            for (int n = 0; n < 8; ++n) {
                float val = dec_e2m1((w[dw] >> (4 * n)) & 15u);
                d = fmaf(hp[n], val, d);
                qq = fmaf(val, val, qq);
            }
        }
#endif
        d += __shfl_xor(d, 1, 64); d += __shfl_xor(d, 2, 64);
        qq += __shfl_xor(qq, 1, 64); qq += __shfl_xor(qq, 2, 64);
        dot[j] = d; qq2[j] = qq;
    }

    const float h2 = ss[0], ldh = ss[1], sig = ss[2], bh = ss[3];

    // candidate A: j == sub
    {
        const float Dc = (sub == 0) ? dot[0] : (sub == 1) ? dot[1] : (sub == 2) ? dot[2] : dot[3];
        const float Qc = (sub == 0) ? qq2[0] : (sub == 1) ? qq2[1] : (sub == 2) ? qq2[2] : qq2[3];
        const float inv_s = sb0.x;
        const float D  = Dc * inv_s;
        const float t2 = Qc * inv_s * inv_s;
        const float lt = logf(fmaxf(1.0f - t2, MIN_NORM));
        const float num = h2 + t2 - 2.0f * D;
        const float dist = logf(fmaxf(num, MIN_NORM)) - sig * lt - (1.0f - sig) * ldh;
        out[(long)b * NC + base + 8 * g + sub] = MARGIN - dist + bh + sb0.y;
    }
    // candidate B: j == sub + 4
    {
        const float Dc = (sub == 0) ? dot[4] : (sub == 1) ? dot[5] : (sub == 2) ? dot[6] : dot[7];
        const float Qc = (sub == 0) ? qq2[4] : (sub == 1) ? qq2[5] : (sub == 2) ? qq2[6] : qq2[7];
        const float inv_s = sb1.x;
        const float D  = Dc * inv_s;
        const float t2 = Qc * inv_s * inv_s;
        const float lt = logf(fmaxf(1.0f - t2, MIN_NORM));
        const float num = h2 + t2 - 2.0f * D;
        const float dist = logf(fmaxf(num, MIN_NORM)) - sig * lt - (1.0f - sig) * ldh;
        out[(long)b * NC + base + 8 * g + 4 + sub] = MARGIN - dist + bh + sb1.y;
    }
}

// ---------------- fallback fp32 path, used only if ws too small ----------------
__global__ __launch_bounds__(256) void head_kernel(
    const int* __restrict__ u_idx, const int* __restrict__ r_idx,
    const float* __restrict__ emb, const float* __restrict__ rel_diag,
    const float* __restrict__ rb1, const float* __restrict__ rb2,
    const float* __restrict__ bias_head, const float* __restrict__ sigma,
    float* __restrict__ head_out, float* __restrict__ scal_out)
{
    const int row = blockIdx.x * 4 + (threadIdx.x >> 6);
    if (row >= B_ROWS) return;
    head_body(row, u_idx, r_idx, emb, rel_diag, rb1, rb2,
              bias_head, sigma, head_out, scal_out);
}

__global__ __launch_bounds__(256) void score_fp32_kernel(
    const int* __restrict__ v_idx, const float* __restrict__ emb,
    const float* __restrict__ bias_tail,
    const float* __restrict__ head, const float* __restrict__ scal,
    float* __restrict__ out)
{
    const int b = blockIdx.y;
    const int base = blockIdx.x * 256;
    const int t = threadIdx.x;
    const int g = t >> 2, sub = t & 3;

    __shared__ float4 sh[DIM / 4];
    __shared__ float ss[4];
    if (t < DIM / 4) sh[t] = ((const float4*)(head + (long)b * DIM))[t];
    if (t < 4) ss[t] = scal[b * 4 + t];

    const int4 v4 = ((const int4*)(v_idx + (long)b * NC + base))[g];
    const int v0 = v4.x, v1 = v4.y, v2 = v4.z, v3 = v4.w;
    __syncthreads();

    float4 h[4];
    #pragma unroll
    for (int k = 0; k < 4; ++k) h[k] = sh[4 * k + sub];

    float4 e[4][4];
    {
        const float4* p0 = (const float4*)(emb + (long)v0 * DIM);
        const float4* p1 = (const float4*)(emb + (long)v1 * DIM);
        const float4* p2 = (const float4*)(emb + (long)v2 * DIM);
        const float4* p3 = (const float4*)(emb + (long)v3 * DIM);
        #pragma unroll
        for (int k = 0; k < 4; ++k) {
            e[0][k] = p0[4 * k + sub];
            e[1][k] = p1[4 * k + sub];
            e[2][k] = p2[4 * k + sub];
            e[3][k] = p3[4 * k + sub];
        }
    }

    float dot[4], e2[4];
    #pragma unroll
    for (int j = 0; j < 4; ++j) {
        float d = 0.0f, qq = 0.0f;
        #pragma unroll
        for (int k = 0; k < 4; ++k) {
            float4 ee = e[j][k]; float4 hh = h[k];
            d = fmaf(hh.x, ee.x, d); d = fmaf(hh.y, ee.y, d);
            d = fmaf(hh.z, ee.z, d); d = fmaf(hh.w, ee.w, d);
            qq = fmaf(ee.x, ee.x, qq); qq = fmaf(ee.y, ee.y, qq);
            qq = fmaf(ee.z, ee.z, qq); qq = fmaf(ee.w, ee.w, qq);
        }
        d += __shfl_xor(d, 1, 64); d += __shfl_xor(d, 2, 64);
        qq += __shfl_xor(qq, 1, 64); qq += __shfl_xor(qq, 2, 64);
        dot[j] = d; e2[j] = qq;
    }

    const float D  = (sub == 0) ? dot[0] : (sub == 1) ? dot[1] : (sub == 2) ? dot[2] : dot[3];
    const float E  = (sub == 0) ? e2[0]  : (sub == 1) ? e2[1]  : (sub == 2) ? e2[2]  : e2[3];
    const int myv  = (sub == 0) ? v0     : (sub == 1) ? v1     : (sub == 2) ? v2     : v3;

    const float h2 = ss[0], ldh = ss[1], sig = ss[2], bh = ss[3];
    const float un = fmaxf(sqrtf(E), MIN_NORM);
    const float tn = tanhf(un);
    const float s = tn / un;
    const float t2 = tn * tn;
    const float num = h2 + t2 - 2.0f * s * D;
    const float dist = logf(fmaxf(num, MIN_NORM))
                     - sig * logf(fmaxf(1.0f - t2, MIN_NORM))
                     - (1.0f - sig) * ldh;
    out[(long)b * NC + base + t] = MARGIN - dist + bh + bias_tail[myv];
}

extern "C" void kernel_launch(void* const* d_in, const int* in_sizes, int n_in,
                              void* d_out, int out_size, void* d_ws, size_t ws_size,
                              hipStream_t stream) {
    const int*   u_idx     = (const int*)d_in[0];
    const int*   r_idx     = (const int*)d_in[1];
    const int*   v_idx     = (const int*)d_in[2];
    const float* emb       = (const float*)d_in[3];
    const float* rel_diag  = (const float*)d_in[4];
    const float* rb1       = (const float*)d_in[5];
    const float* rb2       = (const float*)d_in[6];
    const float* bias_head = (const float*)d_in[7];
    const float* bias_tail = (const float*)d_in[8];
    const float* sigma     = (const float*)d_in[9];

    char* ws = (char*)d_ws;
    float*    head = (float*)ws;                                   // 256 KB
    float*    scal = (float*)(ws + 262144);                        // 16 KB
    uint32_t* tau  = (uint32_t*)(ws + 278528);                     // 6.4 MB fp4
    float2*   sb   = (float2*)(ws + 278528 + (size_t)N_ENT * 32);  // 1.6 MB
    const size_t need = 278528 + (size_t)N_ENT * 32 + (size_t)N_ENT * 8;

    if (ws_size >= need) {
        prep_kernel<<<CONV_BLOCKS + HEAD_BLOCKS, 256, 0, stream>>>(
            u_idx, r_idx, emb, rel_diag, rb1, rb2, bias_head, sigma,
            bias_tail, tau, sb, head, scal);
        score_fp4_kernel<<<dim3(NC / 512, B_ROWS), 256, 0, stream>>>(
            v_idx, tau, sb, head, scal, (float*)d_out);
    } else {
        head_kernel<<<HEAD_BLOCKS, 256, 0, stream>>>(
            u_idx, r_idx, emb, rel_diag, rb1, rb2, bias_head, sigma, head, scal);
        score_fp32_kernel<<<dim3(NC / 256, B_ROWS), 256, 0, stream>>>(
            v_idx, emb, bias_tail, head, scal, (float*)d_out);
    }
}